// Round 4
// baseline (773.486 us; speedup 1.0000x reference)
//
#include <hip/hip_runtime.h>
#include <hip/hip_bf16.h>

#define B_ 2
#define N_ 1024
#define D_ 768
#define E_ 128
#define H_ 16
#define HD_ 48
#define HDP_ 64

typedef short bf16x8 __attribute__((ext_vector_type(8)));
typedef float f32x4 __attribute__((ext_vector_type(4)));

__device__ __forceinline__ unsigned short f2bf(float f) {
    __hip_bfloat16 h = __float2bfloat16(f);
    return *reinterpret_cast<unsigned short*>(&h);
}
__device__ __forceinline__ float bf2f(unsigned short s) {
    return __uint_as_float(((unsigned int)s) << 16);
}

__device__ __forceinline__ bf16x8 ld_frag_f32(const float* __restrict__ p) {
    float4 a = *(const float4*)p;
    float4 b = *(const float4*)(p + 4);
    bf16x8 r;
    r[0] = (short)f2bf(a.x); r[1] = (short)f2bf(a.y);
    r[2] = (short)f2bf(a.z); r[3] = (short)f2bf(a.w);
    r[4] = (short)f2bf(b.x); r[5] = (short)f2bf(b.y);
    r[6] = (short)f2bf(b.z); r[7] = (short)f2bf(b.w);
    return r;
}

// ---------------------------------------------------------------------------
// Kernel 0: prep. y=0: Wo -> hi/lo split. y=1: zero hd-padding of qp/kp.
// ---------------------------------------------------------------------------
__global__ void prep_kernel(const float* __restrict__ Wo,
                            unsigned short* __restrict__ Whi, unsigned short* __restrict__ Wlo,
                            unsigned short* __restrict__ qp, unsigned short* __restrict__ kp)
{
    const int t = blockIdx.x * 256 + threadIdx.x;
    if (blockIdx.y == 0) {
        if (t < D_ * D_) {
            const float xv = Wo[t];
            const unsigned short hi = f2bf(xv);
            Whi[t] = hi;
            Wlo[t] = f2bf(xv - bf2f(hi));
        }
    } else {
        if (t < B_ * H_ * N_ * 2) {
            const int row = t >> 1, half = t & 1;
            uint4 z = {0u, 0u, 0u, 0u};
            *(uint4*)(qp + ((size_t)row << 6) + 48 + half * 8) = z;
            *(uint4*)(kp + ((size_t)row << 6) + 48 + half * 8) = z;
        }
    }
}

// ---------------------------------------------------------------------------
// Kernel 1: projections.  z=0: q -> qp (b,h,n,64) bf16 ; z=1: k -> kp
//           z=2: v^T -> vT (b,h,48,n) ; z=3: g (sigmoid, f32)
// ---------------------------------------------------------------------------
__global__ __launch_bounds__(256) void proj_kernel(
    const float* __restrict__ node, const float* __restrict__ kin,
    const float* __restrict__ Wq, const float* __restrict__ bq,
    const float* __restrict__ Wk, const float* __restrict__ Wv,
    const float* __restrict__ Wg,
    unsigned short* __restrict__ qp, unsigned short* __restrict__ kp,
    unsigned short* __restrict__ vT, float* __restrict__ g)
{
    const int z = blockIdx.z;
    const int lane = threadIdx.x & 63;
    const int w = threadIdx.x >> 6;
    const int wm = w >> 1, wn = w & 1;
    const int lr = lane & 15, lg = lane >> 4;

    const float* A;
    const float* Wm;
    int mbase, nbase;
    if (z == 2) {                    // C[d][tok] = Wv * kin^T
        A = Wv; Wm = kin;
        mbase = blockIdx.y * 64 + wm * 32;   // d rows (768)
        nbase = blockIdx.x * 64 + wn * 32;   // tok cols (2048)
    } else {
        A = (z == 1) ? kin : node;
        Wm = (z == 0) ? Wq : (z == 1) ? Wk : Wg;
        mbase = blockIdx.x * 64 + wm * 32;   // tok rows (2048)
        nbase = blockIdx.y * 64 + wn * 32;   // d cols (768)
    }

    f32x4 acc[2][2] = {};
    for (int k0 = 0; k0 < D_; k0 += 32) {
        bf16x8 af[2], bfm[2];
#pragma unroll
        for (int ms = 0; ms < 2; ++ms)
            af[ms] = ld_frag_f32(A + (size_t)(mbase + ms * 16 + lr) * D_ + k0 + lg * 8);
#pragma unroll
        for (int ns = 0; ns < 2; ++ns)
            bfm[ns] = ld_frag_f32(Wm + (size_t)(nbase + ns * 16 + lr) * D_ + k0 + lg * 8);
#pragma unroll
        for (int ms = 0; ms < 2; ++ms)
#pragma unroll
            for (int ns = 0; ns < 2; ++ns)
                acc[ms][ns] = __builtin_amdgcn_mfma_f32_16x16x32_bf16(
                    af[ms], bfm[ns], acc[ms][ns], 0, 0, 0);
    }

#pragma unroll
    for (int ms = 0; ms < 2; ++ms) {
#pragma unroll
        for (int ns = 0; ns < 2; ++ns) {
#pragma unroll
            for (int r = 0; r < 4; ++r) {
                const int row = mbase + ms * 16 + lg * 4 + r;
                const int col = nbase + ns * 16 + lr;
                float v = acc[ms][ns][r];
                if (z == 0) {
                    v += bq[col];
                    const int b = row >> 10, tok = row & 1023;
                    const int h = col / HD_, hd = col - h * HD_;
                    qp[((size_t)((b * H_ + h) * N_ + tok) << 6) + hd] = f2bf(v);
                } else if (z == 1) {
                    const int b = row >> 10, tok = row & 1023;
                    const int h = col / HD_, hd = col - h * HD_;
                    kp[((size_t)((b * H_ + h) * N_ + tok) << 6) + hd] = f2bf(v);
                } else if (z == 3) {
                    g[(size_t)row * D_ + col] = 1.f / (1.f + __expf(-v));
                } else {  // z==2: row = d, col = tok
                    const int b = col >> 10, tok = col & 1023;
                    const int h = row / HD_, hd = row - h * HD_;
                    vT[((size_t)((b * H_ + h) * HD_ + hd) << 10) + tok] = f2bf(v);
                }
            }
        }
    }
}

// ---------------------------------------------------------------------------
// Kernel 2: FUSED bias + attention.
// Block = (b = id&1 [XCD parity], j-half = (id>>1)&1, i-tile = (id>>2)*16),
// 1024 threads = 16 waves.  Per j-tile of 64:
//   phase A: wave w computes LN+Wz bias for i-row (i0+w) x 64 j -> bias_lds
//   phase B: wave w = head h: swapped QK^T + exp + PV, bias from LDS.
// Outputs partial (O, li) per j-half.
// ---------------------------------------------------------------------------
__global__ __launch_bounds__(1024, 4) void fused_ba(
    const float* __restrict__ edge, const float* __restrict__ lng,
    const float* __restrict__ lnb, const float* __restrict__ Wz,
    const int* __restrict__ mask,
    const unsigned short* __restrict__ qp, const unsigned short* __restrict__ kp,
    const unsigned short* __restrict__ vT,
    float* __restrict__ Op, float* __restrict__ lip)
{
    const int tid = threadIdx.x;
    const int w = tid >> 6;
    const int lane = tid & 63;
    const int lr = lane & 15, lg = lane >> 4;
    const int id = blockIdx.x;
    const int b = id & 1;
    const int jh = (id >> 1) & 1;
    const int i0 = (id >> 2) * 16;
    const int jbase = jh * 512;
    const float scale = 0.14433756729740643f;  // 1/sqrt(48)

    // [j_local][i*17+h] shorts; row stride 273 (odd*... 546B -> bank-staggered)
    __shared__ unsigned short bias_lds[64][273];
    __shared__ unsigned short pt[16][16][40];   // per-wave P tiles [i][j32]

    // Wz B-frags: B[k=e][col=h]
    bf16x8 wzf[4];
#pragma unroll
    for (int ks = 0; ks < 4; ++ks)
#pragma unroll
        for (int e = 0; e < 8; ++e)
            wzf[ks][e] = (short)f2bf(Wz[(ks * 32 + lg * 8 + e) * H_ + lr]);

    // q frags for head h=w (B operand: col=i=lr, k=lg*8+e)
    bf16x8 qf0, qf1;
    {
        const unsigned short* qb =
            qp + (((size_t)(b * H_ + w) * N_ + i0 + lr) << 6) + lg * 8;
        qf0 = *(const bf16x8*)qb;
        qf1 = *(const bf16x8*)(qb + 32);
    }

    float li = 0.f;
    f32x4 ov[3] = {};
    const int i_mine = i0 + w;
    const int* maskp = mask + b * N_;
    const float* erow = edge + (size_t)(b * N_ + i_mine) * N_ * E_;

    for (int jt = 0; jt < 8; ++jt) {
        const int j0 = jbase + jt * 64;

        // ---- phase A: bias for (i_mine, j0..j0+63) ----
#pragma unroll
        for (int pass = 0; pass < 4; ++pass) {
            const float* rp = erow + (size_t)(j0 + pass * 16 + lr) * E_;
            float x[4][8];
            float s = 0.f, sq = 0.f;
#pragma unroll
            for (int ks = 0; ks < 4; ++ks) {
                float4 a = *(const float4*)(rp + ks * 32 + lg * 8);
                float4 bb = *(const float4*)(rp + ks * 32 + lg * 8 + 4);
                x[ks][0] = a.x; x[ks][1] = a.y; x[ks][2] = a.z; x[ks][3] = a.w;
                x[ks][4] = bb.x; x[ks][5] = bb.y; x[ks][6] = bb.z; x[ks][7] = bb.w;
#pragma unroll
                for (int e = 0; e < 8; ++e) {
                    s += x[ks][e];
                    sq = fmaf(x[ks][e], x[ks][e], sq);
                }
            }
            s  += __shfl_xor(s, 16);  s  += __shfl_xor(s, 32);
            sq += __shfl_xor(sq, 16); sq += __shfl_xor(sq, 32);
            const float mean = s * (1.f / 128.f);
            const float var = sq * (1.f / 128.f) - mean * mean;
            const float rs = rsqrtf(var + 1e-5f);
            const float c0 = -mean * rs;

            f32x4 acc = {};
#pragma unroll
            for (int ks = 0; ks < 4; ++ks) {
                bf16x8 af;
#pragma unroll
                for (int e = 0; e < 8; ++e) {
                    const int ee = ks * 32 + lg * 8 + e;
                    const float zn = fmaf(fmaf(x[ks][e], rs, c0), lng[ee], lnb[ee]);
                    af[e] = (short)f2bf(zn);
                }
                acc = __builtin_amdgcn_mfma_f32_16x16x32_bf16(af, wzf[ks], acc, 0, 0, 0);
            }
            // C: row = pass-row (lg*4+r) -> j ; col = h = lr
#pragma unroll
            for (int r = 0; r < 4; ++r) {
                const int jj = j0 + pass * 16 + lg * 4 + r;
                bias_lds[pass * 16 + lg * 4 + r][w * 17 + lr] =
                    f2bf(acc[r] + (1.f - (float)maskp[jj]) * (-1.0e6f));
            }
        }
        __syncthreads();

        // ---- phase B: head h=w ----
#pragma unroll
        for (int half = 0; half < 2; ++half) {
#pragma unroll
            for (int s2 = 0; s2 < 2; ++s2) {
                const int jj0 = j0 + half * 32 + s2 * 16;
                const unsigned short* kb =
                    kp + (((size_t)(b * H_ + w) * N_ + jj0 + lr) << 6) + lg * 8;
                bf16x8 k0 = *(const bf16x8*)kb;
                bf16x8 k1 = *(const bf16x8*)(kb + 32);
                f32x4 t = {};
                t = __builtin_amdgcn_mfma_f32_16x16x32_bf16(k0, qf0, t, 0, 0, 0);
                t = __builtin_amdgcn_mfma_f32_16x16x32_bf16(k1, qf1, t, 0, 0, 0);
                float p[4];
#pragma unroll
                for (int r = 0; r < 4; ++r) {
                    const int jl = half * 32 + s2 * 16 + lg * 4 + r;  // j in tile
                    const float bv = bf2f(bias_lds[jl][lr * 17 + w]); // i=lr, h=w
                    p[r] = __expf(fmaf(t[r], scale, bv));
                    li += p[r];
                }
                ushort4 pk;
                pk.x = f2bf(p[0]); pk.y = f2bf(p[1]);
                pk.z = f2bf(p[2]); pk.w = f2bf(p[3]);
                *(ushort4*)&pt[w][lr][s2 * 16 + lg * 4] = pk;
            }
            bf16x8 pa = *(const bf16x8*)&pt[w][lr][lg * 8];
#pragma unroll
            for (int v = 0; v < 3; ++v) {
                const unsigned short* vb =
                    vT + (((size_t)((b * H_ + w) * HD_ + v * 16 + lr)) << 10) +
                    j0 + half * 32 + lg * 8;
                bf16x8 vf = *(const bf16x8*)vb;
                ov[v] = __builtin_amdgcn_mfma_f32_16x16x32_bf16(pa, vf, ov[v], 0, 0, 0);
            }
        }
        __syncthreads();
    }

    // epilogue: partial row-sums + partial O
    li += __shfl_xor(li, 16);
    li += __shfl_xor(li, 32);
    if (lg == 0)
        lip[(size_t)jh * (B_ * H_ * N_) + (((size_t)(b * H_ + w)) << 10) + i0 + lr] = li;

    float* op = Op + (size_t)jh * (B_ * N_ * D_);
#pragma unroll
    for (int v = 0; v < 3; ++v)
#pragma unroll
        for (int r = 0; r < 4; ++r)
            op[(size_t)(b * N_ + i0 + lg * 4 + r) * D_ + w * HD_ + v * 16 + lr] =
                ov[v][r];
}

// ---------------------------------------------------------------------------
// Kernel 3: combine j-halves + epilogue: x = g * (O0+O1)/(l0+l1) -> hi/lo
// ---------------------------------------------------------------------------
__global__ __launch_bounds__(256) void combine_kernel(
    const float* __restrict__ Op, const float* __restrict__ lip,
    const float* __restrict__ g,
    unsigned short* __restrict__ Xhi, unsigned short* __restrict__ Xlo)
{
    const int row = blockIdx.x;          // b*N + i
    const int b = row >> 10, i = row & 1023;
    for (int c = threadIdx.x; c < D_; c += 256) {
        const int h = c / HD_;
        const size_t lidx = (((size_t)(b * H_ + h)) << 10) + i;
        const float l = lip[lidx] + lip[(size_t)(B_ * H_ * N_) + lidx];
        const size_t off = (size_t)row * D_ + c;
        const float o = (Op[off] + Op[(size_t)(B_ * N_ * D_) + off]) / l;
        const float xv = g[off] * o;
        const unsigned short hi = f2bf(xv);
        Xhi[off] = hi;
        Xlo[off] = f2bf(xv - bf2f(hi));
    }
}

// ---------------------------------------------------------------------------
// Kernel 4: out = X @ Wo.T via split-bf16 (3 MFMA: hi*hi + hi*lo + lo*hi)
// ---------------------------------------------------------------------------
__global__ __launch_bounds__(256) void out_gemm(
    const unsigned short* __restrict__ Xhi, const unsigned short* __restrict__ Xlo,
    const unsigned short* __restrict__ Whi, const unsigned short* __restrict__ Wlo,
    float* __restrict__ out)
{
    const int lane = threadIdx.x & 63;
    const int w = threadIdx.x >> 6;
    const int wm = w >> 1, wn = w & 1;
    const int lr = lane & 15, lg = lane >> 4;
    const int mbase = blockIdx.x * 64 + wm * 32;
    const int nbase = blockIdx.y * 64 + wn * 32;

    f32x4 acc[2][2] = {};
    for (int k0 = 0; k0 < D_; k0 += 32) {
        bf16x8 ah[2], al[2], bh[2], bl[2];
#pragma unroll
        for (int ms = 0; ms < 2; ++ms) {
            const size_t off = (size_t)(mbase + ms * 16 + lr) * D_ + k0 + lg * 8;
            ah[ms] = *(const bf16x8*)(Xhi + off);
            al[ms] = *(const bf16x8*)(Xlo + off);
        }
#pragma unroll
        for (int ns = 0; ns < 2; ++ns) {
            const size_t off = (size_t)(nbase + ns * 16 + lr) * D_ + k0 + lg * 8;
            bh[ns] = *(const bf16x8*)(Whi + off);
            bl[ns] = *(const bf16x8*)(Wlo + off);
        }
#pragma unroll
        for (int ms = 0; ms < 2; ++ms)
#pragma unroll
            for (int ns = 0; ns < 2; ++ns) {
                acc[ms][ns] = __builtin_amdgcn_mfma_f32_16x16x32_bf16(ah[ms], bh[ns], acc[ms][ns], 0, 0, 0);
                acc[ms][ns] = __builtin_amdgcn_mfma_f32_16x16x32_bf16(ah[ms], bl[ns], acc[ms][ns], 0, 0, 0);
                acc[ms][ns] = __builtin_amdgcn_mfma_f32_16x16x32_bf16(al[ms], bh[ns], acc[ms][ns], 0, 0, 0);
            }
    }
#pragma unroll
    for (int ms = 0; ms < 2; ++ms)
#pragma unroll
        for (int ns = 0; ns < 2; ++ns)
#pragma unroll
            for (int r = 0; r < 4; ++r)
                out[(size_t)(mbase + ms * 16 + lg * 4 + r) * D_ + nbase + ns * 16 + lr] =
                    acc[ms][ns][r];
}

// ---------------------------------------------------------------------------
extern "C" void kernel_launch(void* const* d_in, const int* in_sizes, int n_in,
                              void* d_out, int out_size, void* d_ws, size_t ws_size,
                              hipStream_t stream) {
    const float* node = (const float*)d_in[0];
    const float* edge = (const float*)d_in[1];
    const int*   mask = (const int*)d_in[2];
    const float* kin  = (const float*)d_in[3];
    const float* Wq   = (const float*)d_in[4];
    const float* bq   = (const float*)d_in[5];
    const float* Wk   = (const float*)d_in[6];
    const float* Wv   = (const float*)d_in[7];
    const float* Wg   = (const float*)d_in[8];
    const float* lng  = (const float*)d_in[9];
    const float* lnb  = (const float*)d_in[10];
    const float* Wz   = (const float*)d_in[11];
    const float* Wo   = (const float*)d_in[12];
    float* out = (float*)d_out;

    char* ws = (char*)d_ws;
    const size_t qk_bytes = (size_t)B_ * H_ * N_ * HDP_ * 2;        // 4 MiB each
    unsigned short* qp = (unsigned short*)ws;   ws += qk_bytes;
    unsigned short* kp = (unsigned short*)ws;   ws += qk_bytes;
    unsigned short* vT = (unsigned short*)ws;   ws += (size_t)B_ * H_ * HD_ * N_ * 2;
    float* gbuf = (float*)ws;                   ws += (size_t)B_ * N_ * D_ * 4;
    float* Op   = (float*)ws;                   ws += (size_t)2 * B_ * N_ * D_ * 4;
    float* lip  = (float*)ws;                   ws += (size_t)2 * B_ * H_ * N_ * 4;
    unsigned short* Xhi = (unsigned short*)ws;  ws += (size_t)B_ * N_ * D_ * 2;
    unsigned short* Xlo = (unsigned short*)ws;  ws += (size_t)B_ * N_ * D_ * 2;
    unsigned short* Whi = (unsigned short*)ws;  ws += (size_t)D_ * D_ * 2;
    unsigned short* Wlo = (unsigned short*)ws;  ws += (size_t)D_ * D_ * 2;

    prep_kernel<<<dim3(2304, 2), 256, 0, stream>>>(Wo, Whi, Wlo, qp, kp);
    proj_kernel<<<dim3(32, 12, 4), 256, 0, stream>>>(
        node, kin, Wq, bq, Wk, Wv, Wg, qp, kp, vT, gbuf);
    fused_ba<<<dim3(256), 1024, 0, stream>>>(
        edge, lng, lnb, Wz, mask, qp, kp, vT, Op, lip);
    combine_kernel<<<dim3(B_ * N_), 256, 0, stream>>>(Op, lip, gbuf, Xhi, Xlo);
    out_gemm<<<dim3(32, 12), 256, 0, stream>>>(Xhi, Xlo, Whi, Wlo, out);
}

// Round 5
// 494.231 us; speedup vs baseline: 1.5650x; 1.5650x over previous
//
#include <hip/hip_runtime.h>
#include <hip/hip_bf16.h>

#define B_ 2
#define N_ 1024
#define D_ 768
#define E_ 128
#define H_ 16
#define HD_ 48
#define HDP_ 64

typedef short bf16x8 __attribute__((ext_vector_type(8)));
typedef float f32x4 __attribute__((ext_vector_type(4)));

__device__ __forceinline__ unsigned short f2bf(float f) {
    __hip_bfloat16 h = __float2bfloat16(f);
    return *reinterpret_cast<unsigned short*>(&h);
}
__device__ __forceinline__ float bf2f(unsigned short s) {
    return __uint_as_float(((unsigned int)s) << 16);
}

__device__ __forceinline__ bf16x8 ld_frag_f32(const float* __restrict__ p) {
    float4 a = *(const float4*)p;
    float4 b = *(const float4*)(p + 4);
    bf16x8 r;
    r[0] = (short)f2bf(a.x); r[1] = (short)f2bf(a.y);
    r[2] = (short)f2bf(a.z); r[3] = (short)f2bf(a.w);
    r[4] = (short)f2bf(b.x); r[5] = (short)f2bf(b.y);
    r[6] = (short)f2bf(b.z); r[7] = (short)f2bf(b.w);
    return r;
}

// ---------------------------------------------------------------------------
// Kernel 0: prep. y=0: Wo -> hi/lo split. y=1: zero hd-padding of qp/kp.
// ---------------------------------------------------------------------------
__global__ void prep_kernel(const float* __restrict__ Wo,
                            unsigned short* __restrict__ Whi, unsigned short* __restrict__ Wlo,
                            unsigned short* __restrict__ qp, unsigned short* __restrict__ kp)
{
    const int t = blockIdx.x * 256 + threadIdx.x;
    if (blockIdx.y == 0) {
        if (t < D_ * D_) {
            const float xv = Wo[t];
            const unsigned short hi = f2bf(xv);
            Whi[t] = hi;
            Wlo[t] = f2bf(xv - bf2f(hi));
        }
    } else {
        if (t < B_ * H_ * N_ * 2) {
            const int row = t >> 1, half = t & 1;
            uint4 z = {0u, 0u, 0u, 0u};
            *(uint4*)(qp + ((size_t)row << 6) + 48 + half * 8) = z;
            *(uint4*)(kp + ((size_t)row << 6) + 48 + half * 8) = z;
        }
    }
}

// ---------------------------------------------------------------------------
// Kernel 1: projections.  z=0: q -> qp (b,h,n,64) bf16 ; z=1: k -> kp
//           z=2: v^T -> vT (b,h,48,n) ; z=3: g (sigmoid, f32)
// ---------------------------------------------------------------------------
__global__ __launch_bounds__(256) void proj_kernel(
    const float* __restrict__ node, const float* __restrict__ kin,
    const float* __restrict__ Wq, const float* __restrict__ bq,
    const float* __restrict__ Wk, const float* __restrict__ Wv,
    const float* __restrict__ Wg,
    unsigned short* __restrict__ qp, unsigned short* __restrict__ kp,
    unsigned short* __restrict__ vT, float* __restrict__ g)
{
    const int z = blockIdx.z;
    const int lane = threadIdx.x & 63;
    const int w = threadIdx.x >> 6;
    const int wm = w >> 1, wn = w & 1;
    const int lr = lane & 15, lg = lane >> 4;

    const float* A;
    const float* Wm;
    int mbase, nbase;
    if (z == 2) {                    // C[d][tok] = Wv * kin^T
        A = Wv; Wm = kin;
        mbase = blockIdx.y * 64 + wm * 32;   // d rows (768)
        nbase = blockIdx.x * 64 + wn * 32;   // tok cols (2048)
    } else {
        A = (z == 1) ? kin : node;
        Wm = (z == 0) ? Wq : (z == 1) ? Wk : Wg;
        mbase = blockIdx.x * 64 + wm * 32;   // tok rows (2048)
        nbase = blockIdx.y * 64 + wn * 32;   // d cols (768)
    }

    f32x4 acc[2][2] = {};
    for (int k0 = 0; k0 < D_; k0 += 32) {
        bf16x8 af[2], bfm[2];
#pragma unroll
        for (int ms = 0; ms < 2; ++ms)
            af[ms] = ld_frag_f32(A + (size_t)(mbase + ms * 16 + lr) * D_ + k0 + lg * 8);
#pragma unroll
        for (int ns = 0; ns < 2; ++ns)
            bfm[ns] = ld_frag_f32(Wm + (size_t)(nbase + ns * 16 + lr) * D_ + k0 + lg * 8);
#pragma unroll
        for (int ms = 0; ms < 2; ++ms)
#pragma unroll
            for (int ns = 0; ns < 2; ++ns)
                acc[ms][ns] = __builtin_amdgcn_mfma_f32_16x16x32_bf16(
                    af[ms], bfm[ns], acc[ms][ns], 0, 0, 0);
    }

#pragma unroll
    for (int ms = 0; ms < 2; ++ms) {
#pragma unroll
        for (int ns = 0; ns < 2; ++ns) {
#pragma unroll
            for (int r = 0; r < 4; ++r) {
                const int row = mbase + ms * 16 + lg * 4 + r;
                const int col = nbase + ns * 16 + lr;
                float v = acc[ms][ns][r];
                if (z == 0) {
                    v += bq[col];
                    const int b = row >> 10, tok = row & 1023;
                    const int h = col / HD_, hd = col - h * HD_;
                    qp[((size_t)((b * H_ + h) * N_ + tok) << 6) + hd] = f2bf(v);
                } else if (z == 1) {
                    const int b = row >> 10, tok = row & 1023;
                    const int h = col / HD_, hd = col - h * HD_;
                    kp[((size_t)((b * H_ + h) * N_ + tok) << 6) + hd] = f2bf(v);
                } else if (z == 3) {
                    g[(size_t)row * D_ + col] = 1.f / (1.f + __expf(-v));
                } else {  // z==2: row = d, col = tok
                    const int b = col >> 10, tok = col & 1023;
                    const int h = row / HD_, hd = row - h * HD_;
                    vT[((size_t)((b * H_ + h) * HD_ + hd) << 10) + tok] = f2bf(v);
                }
            }
        }
    }
}

// ---------------------------------------------------------------------------
// Kernel 2: pair bias.  NEW: coalesced staging of the 64 edge rows (32KB
// contiguous) into LDS (flat float4 id f = k*256+tid -> 4KB contiguous per
// instruction per block), then identical LN/Wz/MFMA math reading from LDS.
// LDS row stride 132 floats (16B-aligned b128 reads, at the 1KB/8clk floor).
// ---------------------------------------------------------------------------
__global__ __launch_bounds__(256) void bias_kernel(
    const float* __restrict__ edge, const float* __restrict__ lng,
    const float* __restrict__ lnb, const float* __restrict__ Wz,
    const int* __restrict__ mask, unsigned short* __restrict__ bias)
{
    const int tid = threadIdx.x;
    const int lane = tid & 63;
    const int w = tid >> 6;
    const int lr = lane & 15, lg = lane >> 4;
    const size_t row0 = (size_t)blockIdx.x * 64;

    __shared__ float et[64 * 132];
    __shared__ unsigned short tile[16][68];

    // ---- coalesced stage: 2048 float4s, instruction k covers 4KB contiguous
    const float* gbase = edge + row0 * E_;
#pragma unroll
    for (int k = 0; k < 8; ++k) {
        const int f = k * 256 + tid;
        const float4 v = *(const float4*)(gbase + (size_t)f * 4);
        *(float4*)&et[(f >> 5) * 132 + (f & 31) * 4] = v;
    }

    // loop-invariant Wz B-fragments: B[k=e][col=h] (independent of staging)
    bf16x8 wzf[4];
#pragma unroll
    for (int ks = 0; ks < 4; ++ks) {
#pragma unroll
        for (int e = 0; e < 8; ++e) {
            const int ee = ks * 32 + lg * 8 + e;
            wzf[ks][e] = (short)f2bf(Wz[ee * H_ + lr]);
        }
    }
    __syncthreads();

    const float* xr = &et[(w * 16 + lr) * 132];
    float x[4][8];
    float s = 0.f, sq = 0.f;
#pragma unroll
    for (int ks = 0; ks < 4; ++ks) {
        float4 a = *(const float4*)(xr + ks * 32 + lg * 8);
        float4 b = *(const float4*)(xr + ks * 32 + lg * 8 + 4);
        x[ks][0] = a.x; x[ks][1] = a.y; x[ks][2] = a.z; x[ks][3] = a.w;
        x[ks][4] = b.x; x[ks][5] = b.y; x[ks][6] = b.z; x[ks][7] = b.w;
#pragma unroll
        for (int e = 0; e < 8; ++e) { s += x[ks][e]; sq = fmaf(x[ks][e], x[ks][e], sq); }
    }
    s  += __shfl_xor(s, 16);  s  += __shfl_xor(s, 32);
    sq += __shfl_xor(sq, 16); sq += __shfl_xor(sq, 32);
    const float mean = s * (1.f / 128.f);
    const float var = sq * (1.f / 128.f) - mean * mean;
    const float rs = rsqrtf(var + 1e-5f);
    const float c0 = -mean * rs;

    f32x4 acc = {};
#pragma unroll
    for (int ks = 0; ks < 4; ++ks) {
        bf16x8 af;
#pragma unroll
        for (int e = 0; e < 8; ++e) {
            const int ee = ks * 32 + lg * 8 + e;
            const float zn = fmaf(fmaf(x[ks][e], rs, c0), lng[ee], lnb[ee]);
            af[e] = (short)f2bf(zn);
        }
        acc = __builtin_amdgcn_mfma_f32_16x16x32_bf16(af, wzf[ks], acc, 0, 0, 0);
    }

    // fold node mask:  j = (row0&1023) + w*16 + lg*4 + r
    const int bidx = (int)(row0 >> 20);
    const int jb = (int)(row0 & 1023) + w * 16 + lg * 4;
    const int4 mv = *(const int4*)(mask + bidx * N_ + jb);
    const int* mvp = (const int*)&mv;

    // LDS transpose for coalesced bias writes
#pragma unroll
    for (int r = 0; r < 4; ++r)
        tile[lr][w * 16 + lg * 4 + r] =
            f2bf(acc[r] + (1.f - (float)mvp[r]) * (-1.0e6f));
    __syncthreads();

    const int t = threadIdx.x;
    const int h = t >> 4, cc = (t & 15) * 4;
    const int i = (int)((row0 >> 10) & 1023);
    const int j0 = (int)(row0 & 1023);
    ushort4 v4 = *(const ushort4*)&tile[h][cc];
    *(ushort4*)(bias + (((size_t)((bidx * H_ + h) * N_ + i)) << 10) + j0 + cc) = v4;
}

// ---------------------------------------------------------------------------
// Kernel 3: attention, swapped QK^T, no online max, j split across 4 waves
// (wave w owns j in [w*256, w*256+256)), linear combine via LDS at the end.
// ---------------------------------------------------------------------------
__global__ __launch_bounds__(256) void attn_kernel(
    const unsigned short* __restrict__ qp, const unsigned short* __restrict__ kp,
    const unsigned short* __restrict__ vT, const unsigned short* __restrict__ bias,
    const float* __restrict__ g,
    unsigned short* __restrict__ Xhi, unsigned short* __restrict__ Xlo)
{
    const int tid = threadIdx.x;
    const int w = tid >> 6;
    const int lane = tid & 63;
    const int lr = lane & 15, lg = lane >> 4;
    const int bh = blockIdx.x >> 6;    // 0..31
    const int it = blockIdx.x & 63;    // 0..63
    const int b = bh >> 4;
    const int h = bh & 15;
    const int i0 = it * 16;
    const float scale = 0.14433756729740643f;  // 1/sqrt(48)

    __shared__ unsigned short pt[4][16][40];   // per-wave P tiles
    __shared__ float comb[3][64][13];          // partial (ov, li) of waves 1..3

    bf16x8 qf0, qf1;
    {
        const unsigned short* qb = qp + (((size_t)bh * N_ + i0 + lr) << 6) + lg * 8;
        qf0 = *(const bf16x8*)qb;
        qf1 = *(const bf16x8*)(qb + 32);
    }

    float li = 0.f;
    f32x4 ov[3] = {};
    const unsigned short* biasrow =
        bias + ((size_t)bh << 20) + ((size_t)(i0 + lr) << 10);

    const int jlo = w * 256;
    for (int j0 = jlo; j0 < jlo + 256; j0 += 32) {
#pragma unroll
        for (int s = 0; s < 2; ++s) {
            const unsigned short* kb =
                kp + (((size_t)bh * N_ + j0 + s * 16 + lr) << 6) + lg * 8;
            bf16x8 k0 = *(const bf16x8*)kb;
            bf16x8 k1 = *(const bf16x8*)(kb + 32);
            f32x4 t = {};
            t = __builtin_amdgcn_mfma_f32_16x16x32_bf16(k0, qf0, t, 0, 0, 0);
            t = __builtin_amdgcn_mfma_f32_16x16x32_bf16(k1, qf1, t, 0, 0, 0);
            const ushort4 bv = *(const ushort4*)(biasrow + j0 + s * 16 + lg * 4);
            const unsigned short* bvp = (const unsigned short*)&bv;
            float p[4];
#pragma unroll
            for (int r = 0; r < 4; ++r) {
                p[r] = __expf(fmaf(t[r], scale, bf2f(bvp[r])));
                li += p[r];
            }
            ushort4 pk;
            pk.x = f2bf(p[0]); pk.y = f2bf(p[1]);
            pk.z = f2bf(p[2]); pk.w = f2bf(p[3]);
            *(ushort4*)&pt[w][lr][s * 16 + lg * 4] = pk;
        }
        bf16x8 pa = *(const bf16x8*)&pt[w][lr][lg * 8];
#pragma unroll
        for (int v = 0; v < 3; ++v) {
            const unsigned short* vb =
                vT + (((size_t)(bh * HD_ + v * 16 + lr)) << 10) + j0 + lg * 8;
            bf16x8 vf = *(const bf16x8*)vb;
            ov[v] = __builtin_amdgcn_mfma_f32_16x16x32_bf16(pa, vf, ov[v], 0, 0, 0);
        }
    }

    if (w > 0) {
        float* cb = &comb[w - 1][lane][0];
#pragma unroll
        for (int v = 0; v < 3; ++v)
#pragma unroll
            for (int r = 0; r < 4; ++r) cb[v * 4 + r] = ov[v][r];
        cb[12] = li;
    }
    __syncthreads();
    if (w == 0) {
#pragma unroll
        for (int s = 0; s < 3; ++s) {
            const float* cb = &comb[s][lane][0];
#pragma unroll
            for (int v = 0; v < 3; ++v)
#pragma unroll
                for (int r = 0; r < 4; ++r) ov[v][r] += cb[v * 4 + r];
            li += cb[12];
        }
        li += __shfl_xor(li, 16);
        li += __shfl_xor(li, 32);
        float lired[4];
#pragma unroll
        for (int r = 0; r < 4; ++r) lired[r] = __shfl(li, lg * 4 + r);

#pragma unroll
        for (int v = 0; v < 3; ++v) {
#pragma unroll
            for (int r = 0; r < 4; ++r) {
                const size_t row = (size_t)(b * N_ + i0 + lg * 4 + r);
                const int col = h * HD_ + v * 16 + lr;
                const float xv = g[row * D_ + col] * (ov[v][r] / lired[r]);
                const unsigned short hi = f2bf(xv);
                const size_t off = row * D_ + col;
                Xhi[off] = hi;
                Xlo[off] = f2bf(xv - bf2f(hi));
            }
        }
    }
}

// ---------------------------------------------------------------------------
// Kernel 4: out = X @ Wo.T via split-bf16 (3 MFMA: hi*hi + hi*lo + lo*hi)
// ---------------------------------------------------------------------------
__global__ __launch_bounds__(256) void out_gemm(
    const unsigned short* __restrict__ Xhi, const unsigned short* __restrict__ Xlo,
    const unsigned short* __restrict__ Whi, const unsigned short* __restrict__ Wlo,
    float* __restrict__ out)
{
    const int lane = threadIdx.x & 63;
    const int w = threadIdx.x >> 6;
    const int wm = w >> 1, wn = w & 1;
    const int lr = lane & 15, lg = lane >> 4;
    const int mbase = blockIdx.x * 64 + wm * 32;
    const int nbase = blockIdx.y * 64 + wn * 32;

    f32x4 acc[2][2] = {};
    for (int k0 = 0; k0 < D_; k0 += 32) {
        bf16x8 ah[2], al[2], bh[2], bl[2];
#pragma unroll
        for (int ms = 0; ms < 2; ++ms) {
            const size_t off = (size_t)(mbase + ms * 16 + lr) * D_ + k0 + lg * 8;
            ah[ms] = *(const bf16x8*)(Xhi + off);
            al[ms] = *(const bf16x8*)(Xlo + off);
        }
#pragma unroll
        for (int ns = 0; ns < 2; ++ns) {
            const size_t off = (size_t)(nbase + ns * 16 + lr) * D_ + k0 + lg * 8;
            bh[ns] = *(const bf16x8*)(Whi + off);
            bl[ns] = *(const bf16x8*)(Wlo + off);
        }
#pragma unroll
        for (int ms = 0; ms < 2; ++ms)
#pragma unroll
            for (int ns = 0; ns < 2; ++ns) {
                acc[ms][ns] = __builtin_amdgcn_mfma_f32_16x16x32_bf16(ah[ms], bh[ns], acc[ms][ns], 0, 0, 0);
                acc[ms][ns] = __builtin_amdgcn_mfma_f32_16x16x32_bf16(ah[ms], bl[ns], acc[ms][ns], 0, 0, 0);
                acc[ms][ns] = __builtin_amdgcn_mfma_f32_16x16x32_bf16(al[ms], bh[ns], acc[ms][ns], 0, 0, 0);
            }
    }
#pragma unroll
    for (int ms = 0; ms < 2; ++ms)
#pragma unroll
        for (int ns = 0; ns < 2; ++ns)
#pragma unroll
            for (int r = 0; r < 4; ++r)
                out[(size_t)(mbase + ms * 16 + lg * 4 + r) * D_ + nbase + ns * 16 + lr] =
                    acc[ms][ns][r];
}

// ---------------------------------------------------------------------------
extern "C" void kernel_launch(void* const* d_in, const int* in_sizes, int n_in,
                              void* d_out, int out_size, void* d_ws, size_t ws_size,
                              hipStream_t stream) {
    const float* node = (const float*)d_in[0];
    const float* edge = (const float*)d_in[1];
    const int*   mask = (const int*)d_in[2];
    const float* kin  = (const float*)d_in[3];
    const float* Wq   = (const float*)d_in[4];
    const float* bq   = (const float*)d_in[5];
    const float* Wk   = (const float*)d_in[6];
    const float* Wv   = (const float*)d_in[7];
    const float* Wg   = (const float*)d_in[8];
    const float* lng  = (const float*)d_in[9];
    const float* lnb  = (const float*)d_in[10];
    const float* Wz   = (const float*)d_in[11];
    const float* Wo   = (const float*)d_in[12];
    float* out = (float*)d_out;

    char* ws = (char*)d_ws;
    const size_t qk_bytes = (size_t)B_ * H_ * N_ * HDP_ * 2;        // 4 MiB each
    unsigned short* qp = (unsigned short*)ws;   ws += qk_bytes;
    unsigned short* kp = (unsigned short*)ws;   ws += qk_bytes;
    unsigned short* vT = (unsigned short*)ws;   ws += (size_t)B_ * H_ * HD_ * N_ * 2;
    float* gbuf = (float*)ws;                   ws += (size_t)B_ * N_ * D_ * 4;
    unsigned short* bias = (unsigned short*)ws; ws += (size_t)B_ * H_ * N_ * N_ * 2;
    unsigned short* Xhi = (unsigned short*)ws;  ws += (size_t)B_ * N_ * D_ * 2;
    unsigned short* Xlo = (unsigned short*)ws;  ws += (size_t)B_ * N_ * D_ * 2;
    unsigned short* Whi = (unsigned short*)ws;  ws += (size_t)D_ * D_ * 2;
    unsigned short* Wlo = (unsigned short*)ws;  ws += (size_t)D_ * D_ * 2;

    prep_kernel<<<dim3(2304, 2), 256, 0, stream>>>(Wo, Whi, Wlo, qp, kp);
    proj_kernel<<<dim3(32, 12, 4), 256, 0, stream>>>(
        node, kin, Wq, bq, Wk, Wv, Wg, qp, kp, vT, gbuf);
    bias_kernel<<<dim3(32768), 256, 0, stream>>>(edge, lng, lnb, Wz, mask, bias);
    attn_kernel<<<dim3(2048), 256, 0, stream>>>(qp, kp, vT, bias, gbuf, Xhi, Xlo);
    out_gemm<<<dim3(32, 12), 256, 0, stream>>>(Xhi, Xlo, Whi, Wlo, out);
}